// Round 5
// baseline (249.305 us; speedup 1.0000x reference)
//
#include <hip/hip_runtime.h>
#include <math.h>

// S4D scan, fp32 — round 11: r10 compute body (two-plane phase-shifted LDS,
// bulk ds_read_b128, register history scan, 4 VOP3P/double-step) with
// barrier-granularity halved: 512-thread blocks (8 pairs), 512 blocks ->
// TWO independent blocks per CU. Same 4096 waves / 4 per SIMD, but block A's
// __syncthreads drain overlaps block B's compute (1024-thr blocks stalled
// the whole CU at every barrier). Reduce stage-4 (xor8, within a 16-lane
// row) moved from ds_swizzle to DPP row_ror:8 (l+8 mod 16 == l^8).

#define H_  512
#define L_  4096
#define B_  8
#define N2_ 32
#define TC  64           // timesteps per chunk
#define PPB 8            // pairs (waves) per block
#define THREADS 512
#define NCHUNK (L_ / TC) // 64
#define XSTR 68          // x plane row stride (floats): 16B-aligned rows
#define YTSTR 67         // y-transpose row stride

typedef float v2f __attribute__((ext_vector_type(2)));
typedef float v4f __attribute__((ext_vector_type(4)));

__device__ __forceinline__ float bfly1(float v) {   // xor 1: quad_perm [1,0,3,2]
    return __int_as_float(__builtin_amdgcn_update_dpp(
        0, __float_as_int(v), 0xB1, 0xf, 0xf, true));
}
__device__ __forceinline__ float bfly2(float v) {   // xor 2: quad_perm [2,3,0,1]
    return __int_as_float(__builtin_amdgcn_update_dpp(
        0, __float_as_int(v), 0x4E, 0xf, 0xf, true));
}
__device__ __forceinline__ float bfly8(float v) {   // xor 8: row_ror:8 (16-lane row)
    return __int_as_float(__builtin_amdgcn_update_dpp(
        0, __float_as_int(v), 0x128, 0xf, 0xf, true));
}
template <int M>
__device__ __forceinline__ float bflyswz(float v) { // xor M within 32-lane group
    return __int_as_float(__builtin_amdgcn_ds_swizzle(
        __float_as_int(v), (M << 10) | 0x1F));
}

// One double-step: HOUT = dAsq (x) HPREV + dAdB2*xa + dB2*xb, where
// XP = (xa, xb) pre-shifted by the per-phase LDS plane. 4 VOP3P ops.
#define SCAN_STEP(HOUT, HPREV, XP) do {                                        \
      v2f m_, g_, t_;                                                          \
      asm("v_pk_mul_f32 %0, %1, %2 op_sel:[0,1] op_sel_hi:[1,1]"               \
          : "=v"(m_) : "v"(dB2), "v"(XP));                                     \
      asm("v_pk_fma_f32 %0, %1, %2, %3 op_sel:[0,0,0] op_sel_hi:[1,0,1]"       \
          : "=v"(g_) : "v"(dAdB2), "v"(XP), "v"(m_));                          \
      asm("v_pk_fma_f32 %0, %1, %2, %3 op_sel:[1,1,0] op_sel_hi:[1,0,1] neg_lo:[1,0,0]" \
          : "=v"(t_) : "v"(dAsq), "v"(HPREV), "v"(g_));                        \
      asm("v_pk_fma_f32 %0, %1, %2, %3 op_sel:[0,0,0] op_sel_hi:[0,1,1]"       \
          : "=v"(HOUT) : "v"(dAsq), "v"(HPREV), "v"(t_));                      \
    } while (0)

__global__ __launch_bounds__(THREADS, 4) void s4d_scan_kernel(
    const float* __restrict__ x,          // (B, L, H)
    const float* __restrict__ log_dt,     // (H,)
    const float* __restrict__ A_real_log, // (H, N2)
    const float* __restrict__ A_imag,     // (H, N2)
    const float* __restrict__ B_re,       // (H, N2)
    const float* __restrict__ B_im,       // (H, N2)
    const float* __restrict__ C_re,       // (H, N2)
    const float* __restrict__ C_im,       // (H, N2)
    const float* __restrict__ Dv,         // (H,)
    float* __restrict__ out_y,            // (B, L, H)
    float* __restrict__ st_re,            // (B, H, N2) real plane
    float* __restrict__ st_im)            // (B, H, N2) imag plane
{
    // [buf][plane: 0 = staggered (x[j] at slot j+1), 1 = aligned]
    __shared__ __align__(16) float ldsXX[2][2][PPB * XSTR];   // 8.7 KB
    __shared__ float ldsYT[2][PPB * YTSTR];                   // 4.3 KB

    const int tid   = threadIdx.x;
    const int lane  = tid & 63;
    const int sub   = lane & 31;        // mode index
    const int phase = lane >> 5;        // 0 = even-time chain, 1 = odd-time
    const int q     = tid >> 6;         // pair (wave) within block, 0..7
    const int pair  = blockIdx.x * PPB + q;       // == b*H + h
    const int h     = pair & (H_ - 1);
    const int bblk  = blockIdx.x >> 6;            // 64 blocks per batch
    const int h0    = (blockIdx.x & 63) * PPB;    // block's h base

    // ---- per-lane constants (ZOH), mode n = sub; fold w = 2C into input ----
    const float dt = expf(log_dt[h]);
    const int hn = h * N2_ + sub;
    const float Ar = -expf(A_real_log[hn]);
    const float Ai = A_imag[hn];
    const float xr = dt * Ar;
    const float xi = dt * Ai;
    const float ex = expf(xr);
    const float cs = cosf(xi);
    const float sn = sinf(xi);
    const float dAr = ex * cs;
    const float dAi = ex * sn;
    // expm1(dtA)/A, cancellation-safe real part of expm1:
    const float sh  = sinf(0.5f * xi);
    const float emr = expm1f(xr) * cs - 2.0f * sh * sh;
    const float emi = ex * sn;
    const float ia  = 1.0f / (Ar * Ar + Ai * Ai);
    const float tr  = (emr * Ar + emi * Ai) * ia;
    const float ti  = (emi * Ar - emr * Ai) * ia;
    const float Brv = B_re[hn], Biv = B_im[hn];
    const float dBr = Brv * tr - Biv * ti;
    const float dBi = Brv * ti + Biv * tr;
    const float wr = 2.0f * C_re[hn];
    const float wi = 2.0f * C_im[hn];

    v2f dB2;                               // folded dB * w
    dB2.x = wr * dBr - wi * dBi;
    dB2.y = wr * dBi + wi * dBr;
    v2f dAdB2;                             // dA * (folded dB)
    dAdB2.x = dAr * dB2.x - dAi * dB2.y;
    dAdB2.y = dAr * dB2.y + dAi * dB2.x;
    v2f dAsq;                              // dA^2
    dAsq.x = dAr * dAr - dAi * dAi;
    dAsq.y = 2.0f * dAr * dAi;

    const float Dh = Dv[h];

    const float* __restrict__ xrow = x     + (size_t)bblk * L_ * H_ + h0;
    float*       __restrict__ yrow = out_y + (size_t)bblk * L_ * H_ + h0;

    const int j0 = tid >> 3;          // staging t-offset (0..63)
    const int p0 = tid & 7;           // staging h-offset

    // per-lane read bases: this phase's plane, this pair's row, per buffer
    const v4f* xq0 = (const v4f*)&ldsXX[0][phase][q * XSTR];
    const v4f* xq1 = (const v4f*)&ldsXX[1][phase][q * XSTR];

    // ---- prologue: stage chunk 0 (both planes), prefetch chunk 1 ----
    float rx = xrow[(size_t)j0 * H_ + p0];
    ldsXX[0][1][p0 * XSTR + j0]     = rx;
    ldsXX[0][0][p0 * XSTR + j0 + 1] = rx;
    rx = xrow[(size_t)(TC + j0) * H_ + p0];
    const float* xpre = xrow + (size_t)(2 * TC + j0) * H_ + p0;   // chunk 2+
    __syncthreads();

    v2f ucar; ucar.x = 0.f; ucar.y = 0.f;  // carried state (folded 2C*state)
    float xm1 = 0.f;                  // x_{-1} carry (patches staggered slot 0)

    const bool b1 = (sub & 1), b2 = (sub & 2), b4 = (sub & 4),
               b8 = (sub & 8), b16 = (sub & 16);

    for (int c = 0; c < NCHUNK; ++c) {
        const int cb = c & 1;

        // ---- bulk-load this chunk's x pairs (16 x ds_read_b128, broadcast,
        // issued up-front so the waits pipeline) ----
        const v4f* xq = cb ? xq1 : xq0;
        v4f a0[8], a1[8];
#pragma unroll
        for (int i = 0; i < 8; ++i) a0[i] = xq[i];
#pragma unroll
        for (int i = 0; i < 8; ++i) a1[i] = xq[8 + i];

        // stage next chunk's x (both planes); issue global load for chunk c+2
        if (c + 1 < NCHUNK) {
            ldsXX[cb ^ 1][1][p0 * XSTR + j0]     = rx;
            ldsXX[cb ^ 1][0][p0 * XSTR + j0 + 1] = rx;
        }
        if (c + 2 < NCHUNK) { rx = *xpre; xpre += (size_t)TC * H_; }

        // even chain's tau=0 xa = x[-1]: staggered slot 0 is never written
        a0[0].x = phase ? a0[0].x : xm1;
        // inter-chunk x carry: true x[63] from the ALIGNED plane (broadcast)
        xm1 = ldsXX[cb][1][q * XSTR + 63];

        // ---- serial scan: 32 double-steps, 4 VOP3P each, h[t] history ----
        v2f hreg[32];
        SCAN_STEP(hreg[0], ucar, *(const v2f*)&a0[0]);
#pragma unroll
        for (int t = 1; t < 16; ++t) {
            v2f xp;
            if (t & 1) xp = __builtin_shufflevector(a0[t >> 1], a0[t >> 1], 2, 3);
            else       xp = __builtin_shufflevector(a0[t >> 1], a0[t >> 1], 0, 1);
            SCAN_STEP(hreg[t], hreg[t - 1], xp);
        }
#pragma unroll
        for (int t = 16; t < 32; ++t) {
            const int i = (t - 16) >> 1;
            v2f xp;
            if (t & 1) xp = __builtin_shufflevector(a1[i], a1[i], 2, 3);
            else       xp = __builtin_shufflevector(a1[i], a1[i], 0, 1);
            SCAN_STEP(hreg[t], hreg[t - 1], xp);
        }
        ucar = hreg[31];              // inter-chunk carry (reduce won't touch it)

        // ---- 5-stage distributed transpose-reduce over the 32 mode-lanes
        // (independent per 32-lane half); p[j] := hreg[j].x
#pragma unroll
        for (int j = 0; j < 32; j += 2) {
            const float keep = b1 ? hreg[j + 1].x : hreg[j].x;
            const float send = b1 ? hreg[j].x : hreg[j + 1].x;
            hreg[j].x = keep + bfly1(send);
        }
#pragma unroll
        for (int j = 0; j < 32; j += 4) {
            const float keep = b2 ? hreg[j + 2].x : hreg[j].x;
            const float send = b2 ? hreg[j].x : hreg[j + 2].x;
            hreg[j].x = keep + bfly2(send);
        }
#pragma unroll
        for (int j = 0; j < 32; j += 8) {
            const float keep = b4 ? hreg[j + 4].x : hreg[j].x;
            const float send = b4 ? hreg[j].x : hreg[j + 4].x;
            hreg[j].x = keep + bflyswz<4>(send);
        }
#pragma unroll
        for (int j = 0; j < 32; j += 16) {
            const float keep = b8 ? hreg[j + 8].x : hreg[j].x;
            const float send = b8 ? hreg[j].x : hreg[j + 8].x;
            hreg[j].x = keep + bfly8(send);       // DPP row_ror:8 == xor8
        }
        {
            const float keep = b16 ? hreg[16].x : hreg[0].x;
            const float send = b16 ? hreg[0].x : hreg[16].x;
            hreg[0].x = keep + bflyswz<16>(send);
        }

        // ---- epilogue: lane holds y-sum for t = 2*sub + phase ----
        {
            const int myt  = (sub << 1) | phase;
            const float xv = ldsXX[cb][1][q * XSTR + myt];
            const float y  = fmaf(Dh, xv, hreg[0].x);
            // gelu(y) ~= y * sigmoid(2*sqrt(2/pi)*(y + 0.044715 y^3))
            const float y2  = y * y;
            const float arg = y * fmaf(-0.10294502f, y2, -2.30218425f);
            const float e   = __builtin_amdgcn_exp2f(arg);
            const float gy  = y * __builtin_amdgcn_rcpf(1.0f + e);
            ldsYT[cb][q * YTSTR + myt] = gy;
        }
        __syncthreads();   // YT visible; next x-tile staged; prev reads done

        // coalesced y store: thread e -> (t = e>>3, h = e&7)
        yrow[(size_t)(c * TC + (tid >> 3)) * H_ + (tid & 7)] =
            ldsYT[cb][(tid & 7) * YTSTR + (tid >> 3)];
    }

    // ---- final state: odd chain's ucar == u_L (folded); unfold by conj(w)/|w|^2
    if (phase) {
        const float iw = 1.0f / (wr * wr + wi * wi);
        const float sr = (ucar.x * wr + ucar.y * wi) * iw;
        const float si = (ucar.y * wr - ucar.x * wi) * iw;
        st_re[(size_t)pair * N2_ + sub] = sr;
        st_im[(size_t)pair * N2_ + sub] = si;
    }
}

extern "C" void kernel_launch(void* const* d_in, const int* in_sizes, int n_in,
                              void* d_out, int out_size, void* d_ws, size_t ws_size,
                              hipStream_t stream) {
    (void)in_sizes; (void)n_in; (void)d_ws; (void)ws_size; (void)out_size;
    const float* x    = (const float*)d_in[0];
    const float* ldt  = (const float*)d_in[1];
    const float* Arl  = (const float*)d_in[2];
    const float* Aim  = (const float*)d_in[3];
    const float* Bre  = (const float*)d_in[4];
    const float* Bim  = (const float*)d_in[5];
    const float* Cre  = (const float*)d_in[6];
    const float* Cim  = (const float*)d_in[7];
    const float* Dv   = (const float*)d_in[8];
    float* out = (float*)d_out;
    float* st_re = out + (size_t)B_ * L_ * H_;       // ys first
    float* st_im = st_re + (size_t)B_ * H_ * N2_;    // then imag plane

    dim3 grid(B_ * H_ / PPB);   // 512 blocks -> 2 per CU, 4 waves each
    dim3 block(THREADS);        // 512 threads = 8 pairs, 1 wave/pair
    hipLaunchKernelGGL(s4d_scan_kernel, grid, block, 0, stream,
                       x, ldt, Arl, Aim, Bre, Bim, Cre, Cim, Dv, out, st_re, st_im);
}

// Round 6
// 243.588 us; speedup vs baseline: 1.0235x; 1.0235x over previous
//
#include <hip/hip_runtime.h>
#include <math.h>

// S4D scan, fp32 — round 12: r11 structure plus
//  (1) XCD-bijective block swizzle: lb = (hw%8)*64 + hw/8 -> each XCD owns
//      one batch, 64B x-lines consumed within one XCD (fixes r11's 2x FETCH).
//  (2) x pairs loaded as 32 independent v2f (merge target ds_read2_b64, not
//      b128): XSTR=66 keeps row bases 8B-but-not-16B aligned so the
//      vectorizer cannot form b128 quads -> no half-quad extraction movs;
//      every xp is a clean even-aligned pair feeding VOP3P directly.
//  (3) transpose-reduce masks {1,2,7,8,16}: stage-3 xor4(ds_swizzle) ->
//      xor7 (DPP row_half_mirror, add-fusable). Test functionals are the
//      dual basis: b1=par(sub&5), b2=par(sub&6), b3=bit2, b4=bit3, b5=bit4;
//      final slot s = b1 | b2<<1 | b3<<2 | b4<<3 | b5<<4 (bijective).
// 512-thr blocks (8 pairs), 512 blocks, 2 blocks/CU, 4 waves/SIMD.

#define H_  512
#define L_  4096
#define B_  8
#define N2_ 32
#define TC  64           // timesteps per chunk
#define PPB 8            // pairs (waves) per block
#define THREADS 512
#define NCHUNK (L_ / TC) // 64
#define XSTR 66          // x plane row stride (floats): 8B-aligned, NOT 16B
#define YTSTR 67         // y-transpose row stride

typedef float v2f __attribute__((ext_vector_type(2)));

__device__ __forceinline__ float bfly1(float v) {   // xor 1: quad_perm [1,0,3,2]
    return __int_as_float(__builtin_amdgcn_update_dpp(
        0, __float_as_int(v), 0xB1, 0xf, 0xf, true));
}
__device__ __forceinline__ float bfly2(float v) {   // xor 2: quad_perm [2,3,0,1]
    return __int_as_float(__builtin_amdgcn_update_dpp(
        0, __float_as_int(v), 0x4E, 0xf, 0xf, true));
}
__device__ __forceinline__ float bfly7(float v) {   // xor 7: row_half_mirror
    return __int_as_float(__builtin_amdgcn_update_dpp(
        0, __float_as_int(v), 0x141, 0xf, 0xf, true));
}
__device__ __forceinline__ float bfly8(float v) {   // xor 8: row_ror:8
    return __int_as_float(__builtin_amdgcn_update_dpp(
        0, __float_as_int(v), 0x128, 0xf, 0xf, true));
}
__device__ __forceinline__ float bflyswz16(float v) { // xor 16 (32-lane group)
    return __int_as_float(__builtin_amdgcn_ds_swizzle(
        __float_as_int(v), (16 << 10) | 0x1F));
}

// One double-step: HOUT = dAsq (x) HPREV + dAdB2*xa + dB2*xb, where
// XP = (xa, xb) pre-shifted by the per-phase LDS plane. 4 VOP3P ops.
#define SCAN_STEP(HOUT, HPREV, XP) do {                                        \
      v2f m_, g_, t_;                                                          \
      asm("v_pk_mul_f32 %0, %1, %2 op_sel:[0,1] op_sel_hi:[1,1]"               \
          : "=v"(m_) : "v"(dB2), "v"(XP));                                     \
      asm("v_pk_fma_f32 %0, %1, %2, %3 op_sel:[0,0,0] op_sel_hi:[1,0,1]"       \
          : "=v"(g_) : "v"(dAdB2), "v"(XP), "v"(m_));                          \
      asm("v_pk_fma_f32 %0, %1, %2, %3 op_sel:[1,1,0] op_sel_hi:[1,0,1] neg_lo:[1,0,0]" \
          : "=v"(t_) : "v"(dAsq), "v"(HPREV), "v"(g_));                        \
      asm("v_pk_fma_f32 %0, %1, %2, %3 op_sel:[0,0,0] op_sel_hi:[0,1,1]"       \
          : "=v"(HOUT) : "v"(dAsq), "v"(HPREV), "v"(t_));                      \
    } while (0)

__global__ __launch_bounds__(THREADS, 4) void s4d_scan_kernel(
    const float* __restrict__ x,          // (B, L, H)
    const float* __restrict__ log_dt,     // (H,)
    const float* __restrict__ A_real_log, // (H, N2)
    const float* __restrict__ A_imag,     // (H, N2)
    const float* __restrict__ B_re,       // (H, N2)
    const float* __restrict__ B_im,       // (H, N2)
    const float* __restrict__ C_re,       // (H, N2)
    const float* __restrict__ C_im,       // (H, N2)
    const float* __restrict__ Dv,         // (H,)
    float* __restrict__ out_y,            // (B, L, H)
    float* __restrict__ st_re,            // (B, H, N2) real plane
    float* __restrict__ st_im)            // (B, H, N2) imag plane
{
    // [buf][plane: 0 = staggered (x[j] at slot j+1), 1 = aligned]
    __shared__ float ldsXX[2][2][PPB * XSTR];   // 8.4 KB
    __shared__ float ldsYT[2][PPB * YTSTR];     // 4.3 KB

    // XCD-bijective swizzle: hw blocks round-robin XCDs (hw%8); give XCD k
    // the contiguous logical range [k*64, k*64+64) = one full batch.
    const int lb    = ((int)blockIdx.x & 7) * 64 + ((int)blockIdx.x >> 3);

    const int tid   = threadIdx.x;
    const int lane  = tid & 63;
    const int sub   = lane & 31;        // mode index
    const int phase = lane >> 5;        // 0 = even-time chain, 1 = odd-time
    const int q     = tid >> 6;         // pair (wave) within block, 0..7
    const int pair  = lb * PPB + q;               // == b*H + h
    const int h     = pair & (H_ - 1);
    const int bblk  = lb >> 6;                    // 64 blocks per batch
    const int h0    = (lb & 63) * PPB;            // block's h base

    // ---- per-lane constants (ZOH), mode n = sub; fold w = 2C into input ----
    const float dt = expf(log_dt[h]);
    const int hn = h * N2_ + sub;
    const float Ar = -expf(A_real_log[hn]);
    const float Ai = A_imag[hn];
    const float xr = dt * Ar;
    const float xi = dt * Ai;
    const float ex = expf(xr);
    const float cs = cosf(xi);
    const float sn = sinf(xi);
    const float dAr = ex * cs;
    const float dAi = ex * sn;
    // expm1(dtA)/A, cancellation-safe real part of expm1:
    const float sh  = sinf(0.5f * xi);
    const float emr = expm1f(xr) * cs - 2.0f * sh * sh;
    const float emi = ex * sn;
    const float ia  = 1.0f / (Ar * Ar + Ai * Ai);
    const float tr  = (emr * Ar + emi * Ai) * ia;
    const float ti  = (emi * Ar - emr * Ai) * ia;
    const float Brv = B_re[hn], Biv = B_im[hn];
    const float dBr = Brv * tr - Biv * ti;
    const float dBi = Brv * ti + Biv * tr;
    const float wr = 2.0f * C_re[hn];
    const float wi = 2.0f * C_im[hn];

    v2f dB2;                               // folded dB * w
    dB2.x = wr * dBr - wi * dBi;
    dB2.y = wr * dBi + wi * dBr;
    v2f dAdB2;                             // dA * (folded dB)
    dAdB2.x = dAr * dB2.x - dAi * dB2.y;
    dAdB2.y = dAr * dB2.y + dAi * dB2.x;
    v2f dAsq;                              // dA^2
    dAsq.x = dAr * dAr - dAi * dAi;
    dAsq.y = 2.0f * dAr * dAi;

    const float Dh = Dv[h];

    const float* __restrict__ xrow = x     + (size_t)bblk * L_ * H_ + h0;
    float*       __restrict__ yrow = out_y + (size_t)bblk * L_ * H_ + h0;

    const int j0 = tid >> 3;          // staging t-offset (0..63)
    const int p0 = tid & 7;           // staging h-offset

    // per-lane read bases: this phase's plane, this pair's row, per buffer
    const v2f* xq0 = (const v2f*)&ldsXX[0][phase][q * XSTR];
    const v2f* xq1 = (const v2f*)&ldsXX[1][phase][q * XSTR];

    // ---- prologue: stage chunk 0 (both planes), prefetch chunk 1 ----
    float rx = xrow[(size_t)j0 * H_ + p0];
    ldsXX[0][1][p0 * XSTR + j0]     = rx;
    ldsXX[0][0][p0 * XSTR + j0 + 1] = rx;
    rx = xrow[(size_t)(TC + j0) * H_ + p0];
    const float* xpre = xrow + (size_t)(2 * TC + j0) * H_ + p0;   // chunk 2+
    __syncthreads();

    v2f ucar; ucar.x = 0.f; ucar.y = 0.f;  // carried state (folded 2C*state)
    float xm1 = 0.f;                  // x_{-1} carry (patches staggered slot 0)

    // transpose-reduce test functionals (dual basis of masks {1,2,7,8,16}):
    const bool b1 = ((sub ^ (sub >> 2)) & 1);          // par(sub & 0b00101)
    const bool b2 = (((sub >> 1) ^ (sub >> 2)) & 1);   // par(sub & 0b00110)
    const bool b3 = (sub & 4), b4 = (sub & 8), b5 = (sub & 16);
    const int  slot = (b1 ? 1 : 0) | (b2 ? 2 : 0) | (b3 ? 4 : 0)
                    | (b4 ? 8 : 0) | (b5 ? 16 : 0);
    const int  myt  = (slot << 1) | phase;             // this lane's timestep

    for (int c = 0; c < NCHUNK; ++c) {
        const int cb = c & 1;

        // ---- bulk-load this chunk's x pairs (32 x v2f, 8B-aligned; merge
        // target is ds_read2_b64 -> every pair is a clean even reg pair) ----
        const v2f* xq = cb ? xq1 : xq0;
        v2f a0[16], a1[16];
#pragma unroll
        for (int i = 0; i < 16; ++i) a0[i] = xq[i];
#pragma unroll
        for (int i = 0; i < 16; ++i) a1[i] = xq[16 + i];

        // stage next chunk's x (both planes); issue global load for chunk c+2
        if (c + 1 < NCHUNK) {
            ldsXX[cb ^ 1][1][p0 * XSTR + j0]     = rx;
            ldsXX[cb ^ 1][0][p0 * XSTR + j0 + 1] = rx;
        }
        if (c + 2 < NCHUNK) { rx = *xpre; xpre += (size_t)TC * H_; }

        // even chain's tau=0 xa = x[-1]: staggered slot 0 is never written
        a0[0].x = phase ? a0[0].x : xm1;
        // inter-chunk x carry: true x[63] from the ALIGNED plane (broadcast)
        xm1 = ldsXX[cb][1][q * XSTR + 63];

        // ---- serial scan: 32 double-steps, 4 VOP3P each, h[t] history ----
        v2f hreg[32];
        SCAN_STEP(hreg[0], ucar, a0[0]);
#pragma unroll
        for (int t = 1; t < 16; ++t) SCAN_STEP(hreg[t], hreg[t - 1], a0[t]);
#pragma unroll
        for (int t = 16; t < 32; ++t) SCAN_STEP(hreg[t], hreg[t - 1], a1[t - 16]);
        ucar = hreg[31];              // inter-chunk carry (reduce won't touch it)

        // ---- 5-stage distributed transpose-reduce over the 32 mode-lanes
        // masks {1,2,7,8,16}; keep-high decided by the dual-basis bools ----
#pragma unroll
        for (int j = 0; j < 32; j += 2) {
            const float keep = b1 ? hreg[j + 1].x : hreg[j].x;
            const float send = b1 ? hreg[j].x : hreg[j + 1].x;
            hreg[j].x = keep + bfly1(send);
        }
#pragma unroll
        for (int j = 0; j < 32; j += 4) {
            const float keep = b2 ? hreg[j + 2].x : hreg[j].x;
            const float send = b2 ? hreg[j].x : hreg[j + 2].x;
            hreg[j].x = keep + bfly2(send);
        }
#pragma unroll
        for (int j = 0; j < 32; j += 8) {
            const float keep = b3 ? hreg[j + 4].x : hreg[j].x;
            const float send = b3 ? hreg[j].x : hreg[j + 4].x;
            hreg[j].x = keep + bfly7(send);       // DPP row_half_mirror
        }
#pragma unroll
        for (int j = 0; j < 32; j += 16) {
            const float keep = b4 ? hreg[j + 8].x : hreg[j].x;
            const float send = b4 ? hreg[j].x : hreg[j + 8].x;
            hreg[j].x = keep + bfly8(send);       // DPP row_ror:8
        }
        {
            const float keep = b5 ? hreg[16].x : hreg[0].x;
            const float send = b5 ? hreg[0].x : hreg[16].x;
            hreg[0].x = keep + bflyswz16(send);
        }

        // ---- epilogue: lane holds y-sum for t = myt ----
        {
            const float xv = ldsXX[cb][1][q * XSTR + myt];
            const float y  = fmaf(Dh, xv, hreg[0].x);
            // gelu(y) ~= y * sigmoid(2*sqrt(2/pi)*(y + 0.044715 y^3))
            const float y2  = y * y;
            const float arg = y * fmaf(-0.10294502f, y2, -2.30218425f);
            const float e   = __builtin_amdgcn_exp2f(arg);
            const float gy  = y * __builtin_amdgcn_rcpf(1.0f + e);
            ldsYT[cb][q * YTSTR + myt] = gy;
        }
        __syncthreads();   // YT visible; next x-tile staged; prev reads done

        // coalesced y store: thread e -> (t = e>>3, h = e&7)
        yrow[(size_t)(c * TC + (tid >> 3)) * H_ + (tid & 7)] =
            ldsYT[cb][(tid & 7) * YTSTR + (tid >> 3)];
    }

    // ---- final state: odd chain's ucar == u_L (folded); unfold by conj(w)/|w|^2
    if (phase) {
        const float iw = 1.0f / (wr * wr + wi * wi);
        const float sr = (ucar.x * wr + ucar.y * wi) * iw;
        const float si = (ucar.y * wr - ucar.x * wi) * iw;
        st_re[(size_t)pair * N2_ + sub] = sr;
        st_im[(size_t)pair * N2_ + sub] = si;
    }
}

extern "C" void kernel_launch(void* const* d_in, const int* in_sizes, int n_in,
                              void* d_out, int out_size, void* d_ws, size_t ws_size,
                              hipStream_t stream) {
    (void)in_sizes; (void)n_in; (void)d_ws; (void)ws_size; (void)out_size;
    const float* x    = (const float*)d_in[0];
    const float* ldt  = (const float*)d_in[1];
    const float* Arl  = (const float*)d_in[2];
    const float* Aim  = (const float*)d_in[3];
    const float* Bre  = (const float*)d_in[4];
    const float* Bim  = (const float*)d_in[5];
    const float* Cre  = (const float*)d_in[6];
    const float* Cim  = (const float*)d_in[7];
    const float* Dv   = (const float*)d_in[8];
    float* out = (float*)d_out;
    float* st_re = out + (size_t)B_ * L_ * H_;       // ys first
    float* st_im = st_re + (size_t)B_ * H_ * N2_;    // then imag plane

    dim3 grid(B_ * H_ / PPB);   // 512 blocks -> 2 per CU, 4 waves each
    dim3 block(THREADS);        // 512 threads = 8 pairs, 1 wave/pair
    hipLaunchKernelGGL(s4d_scan_kernel, grid, block, 0, stream,
                       x, ldt, Arl, Aim, Bre, Bim, Cre, Cim, Dv, out, st_re, st_im);
}